// Round 14
// baseline (271.835 us; speedup 1.0000x reference)
//
#include <hip/hip_runtime.h>
#include <math.h>

// Problem constants
#define B_  2
#define S_  2048
#define E_  768
#define H_  12
#define HD_ 64
#define M_  (B_ * S_)     // 4096 rows
#define N3E (3 * E_)      // 2304

typedef __attribute__((ext_vector_type(8)))  short short8;      // 8 bf16
typedef __attribute__((ext_vector_type(8)))  _Float16 half8;    // 8 fp16
typedef __attribute__((ext_vector_type(4)))  _Float16 half4;
typedef __attribute__((ext_vector_type(2)))  _Float16 half2_t;
typedef __attribute__((ext_vector_type(4)))  float floatx4;     // 16x16 MFMA C/D
typedef __attribute__((ext_vector_type(16))) float floatx16;    // 32x32 MFMA C/D

// fold 1/sqrt(64) * log2(e) into q so softmax is a bare v_exp_f32 (exp2)
#define QSCALE 0.18033688011112042f

// packs per 64-row n-tile of fragment-ordered weights: 12 kb * 2 kk * 4 j * 64
#define WTILE 6144
#define NPQ   (36 * WTILE)   // Wqkv packs = 221184
#define NPO   (12 * WTILE)   // Wo packs   = 73728

// round-to-nearest-even fp32 -> bf16
__device__ inline unsigned short f2bf(float f) {
  union { float f; unsigned u; } a; a.f = f;
  unsigned r = a.u + 0x7fff + ((a.u >> 16) & 1);
  return (unsigned short)(r >> 16);
}
// round-half-up (2 VALU ops; still <= 0.5 ulp)
__device__ inline unsigned short f2bf_fast(float f) {
  union { float f; unsigned u; } a; a.f = f;
  return (unsigned short)((a.u + 0x8000u) >> 16);
}
// packed fp32x2 -> fp16x2 (single v_cvt_pkrtz_f16_f32)
__device__ inline half2_t pkrtz(float a, float b) {
  return __builtin_bit_cast(half2_t, __builtin_amdgcn_cvt_pkrtz(a, b));
}
// raw v_exp_f32 via the intrinsic (compiler-managed hazards; R12's inline-asm
// version corrupted results — hazard recognizer can't see through asm)
__device__ inline float fexp2(float x) { return __builtin_amdgcn_exp2f(x); }

// ---------------------------------------------------------------------------
// Kernel 1: fused aux pass.
//  blocks [0,1024):    LayerNorm -> bf16 xn (one wave per row)
//  blocks [1024,2176): convert Wqkv/Wo fp32 -> bf16 in MFMA-FRAGMENT order
// ---------------------------------------------------------------------------
__global__ __launch_bounds__(256) void aux_kernel(
    const float* __restrict__ x, const float* __restrict__ gamma,
    const float* __restrict__ beta, unsigned short* __restrict__ xnb,
    const float* __restrict__ Wqkv, const float* __restrict__ Wo,
    unsigned short* __restrict__ wqf, unsigned short* __restrict__ wof) {
  const int bid = blockIdx.x;
  if (bid < M_ / 4) {
    const int wv = threadIdx.x >> 6, lane = threadIdx.x & 63;
    const int row = bid * 4 + wv;
    const float* xr = x + (size_t)row * E_;

    float4 a = ((const float4*)xr)[lane];
    float4 b = ((const float4*)xr)[lane + 64];
    float4 c = ((const float4*)xr)[lane + 128];

    float s  = (a.x + a.y) + (a.z + a.w) + (b.x + b.y) + (b.z + b.w)
             + (c.x + c.y) + (c.z + c.w);
    float s2 = a.x*a.x + a.y*a.y + a.z*a.z + a.w*a.w
             + b.x*b.x + b.y*b.y + b.z*b.z + b.w*b.w
             + c.x*c.x + c.y*c.y + c.z*c.z + c.w*c.w;
#pragma unroll
    for (int o = 32; o > 0; o >>= 1) {
      s  += __shfl_xor(s, o);
      s2 += __shfl_xor(s2, o);
    }
    const float mu  = s * (1.0f / E_);
    const float var = s2 * (1.0f / E_) - mu * mu;
    const float rs  = rsqrtf(var + 1e-5f);

    const float4* gp = (const float4*)gamma;
    const float4* bp = (const float4*)beta;
    ushort4* xo = (ushort4*)(xnb + (size_t)row * E_);

    float4 vin[3] = {a, b, c};
#pragma unroll
    for (int j = 0; j < 3; j++) {
      float4 g = gp[lane + 64 * j];
      float4 be = bp[lane + 64 * j];
      float4 v = vin[j];
      ushort4 r;
      r.x = f2bf((v.x - mu) * rs * g.x + be.x);
      r.y = f2bf((v.y - mu) * rs * g.y + be.y);
      r.z = f2bf((v.z - mu) * rs * g.z + be.z);
      r.w = f2bf((v.w - mu) * rs * g.w + be.w);
      xo[lane + 64 * j] = r;
    }
  } else {
    int p = (bid - M_ / 4) * 256 + threadIdx.x;
    const float* src; unsigned short* dst;
    if (p < NPQ) { src = Wqkv; dst = wqf; }
    else         { src = Wo;   dst = wof; p -= NPQ; }
    const int nt = p / WTILE, r = p % WTILE;
    const int kb = r >> 9, r2 = r & 511;
    const int kk = r2 >> 8, r3 = r2 & 255;
    const int j = r3 >> 6, lane = r3 & 63;
    const int row = nt * 64 + j * 16 + (lane & 15);
    const int col = kb * 64 + kk * 32 + (lane >> 4) * 8;
    const float* sp = src + (size_t)row * 768 + col;
    float4 f0 = *(const float4*)(sp);
    float4 f1 = *(const float4*)(sp + 4);
    unsigned short* dp = dst + (size_t)p * 8;
    ushort4 r0, r1;
    r0.x = f2bf(f0.x); r0.y = f2bf(f0.y); r0.z = f2bf(f0.z); r0.w = f2bf(f0.w);
    r1.x = f2bf(f1.x); r1.y = f2bf(f1.y); r1.z = f2bf(f1.z); r1.w = f2bf(f1.w);
    *(ushort4*)(dp)     = r0;
    *(ushort4*)(dp + 4) = r1;
  }
}

// ---------------------------------------------------------------------------
// Kernel 2/4: bf16 MFMA GEMM with DIRECT global B-fragment loads.
// NI=2: 128-row tiles (QKV); NI=1: 64-row tiles (proj).
// mode 0 epilogues: q/k via swapped mfma -> d-OCT layout
//   [bh][s>>5][d>>3][s&31][8]; v -> fp16 frag layout.
// mode 1: fp32 out[M][768] = C + bias.
// ---------------------------------------------------------------------------
template <int NI>
__global__ __launch_bounds__(256) void bgemm_kernel(
    const unsigned short* __restrict__ A, const unsigned short* __restrict__ Wf,
    const float* __restrict__ bias, int mode,
    unsigned short* __restrict__ qbf, unsigned short* __restrict__ kbf,
    _Float16* __restrict__ vth, float* __restrict__ out) {
  constexpr int BM = 64 * NI;
  __shared__ __align__(16) unsigned short As[BM * 64];

  const int t  = threadIdx.x;
  const int ln = t & 63, wv = t >> 6;
  const int lr = ln & 15, lg = ln >> 4;
  const int m0 = blockIdx.x * BM, n0 = blockIdx.y * 64;
  const int w  = (mode == 1) ? 3 : (blockIdx.y % 3);

  const int srow = ln >> 3;          // 0..7
  const int scol = (ln & 7) * 8;     // k-offset

  const unsigned short* Ag = A + (size_t)(m0 + wv * (BM / 4) + srow) * 768 + scol;
  const unsigned short* Wt = Wf + (size_t)blockIdx.y * (WTILE * 8);

  floatx4 acc[NI][4];
#pragma unroll
  for (int i = 0; i < NI; i++)
#pragma unroll
    for (int j = 0; j < 4; j++) acc[i][j] = (floatx4){0.f, 0.f, 0.f, 0.f};

  for (int kb = 0; kb < 12; kb++) {
    __syncthreads();
#pragma unroll
    for (int j = 0; j < BM / 32; j++)
      __builtin_amdgcn_global_load_lds(
          (const __attribute__((address_space(1))) void*)(Ag + kb * 64 + j * 8 * 768),
          (__attribute__((address_space(3))) void*)(&As[(wv * (BM / 4) + j * 8) * 64]),
          16, 0, 0);
    // B fragments straight from global; drained by the barrier's vmcnt(0).
    short8 bfr[8];
#pragma unroll
    for (int u = 0; u < 8; u++)
      bfr[u] = *(const short8*)&Wt[(size_t)kb * 4096 + u * 512 + ln * 8];
    __syncthreads();

#pragma unroll
    for (int kk = 0; kk < 2; kk++) {
      short8 af[NI];
#pragma unroll
      for (int i = 0; i < NI; i++)
        af[i] = *(const short8*)&As[(wv * (BM / 4) + i * 16 + lr) * 64 + kk * 32 + lg * 8];
      if (w < 2) {  // swapped: C/D rows = n(d), cols = m(s)
#pragma unroll
        for (int i = 0; i < NI; i++)
#pragma unroll
          for (int j = 0; j < 4; j++)
            acc[i][j] = __builtin_amdgcn_mfma_f32_16x16x32_bf16(bfr[kk * 4 + j], af[i], acc[i][j], 0, 0, 0);
      } else {      // normal: C/D rows = m(s), cols = n(d)
#pragma unroll
        for (int i = 0; i < NI; i++)
#pragma unroll
          for (int j = 0; j < 4; j++)
            acc[i][j] = __builtin_amdgcn_mfma_f32_16x16x32_bf16(af[i], bfr[kk * 4 + j], acc[i][j], 0, 0, 0);
      }
    }
  }

  if (mode == 1) {
#pragma unroll
    for (int i = 0; i < NI; i++) {
      const int grow0 = m0 + wv * (BM / 4) + i * 16 + lg * 4;
#pragma unroll
      for (int j = 0; j < 4; j++) {
        const int gcol = n0 + j * 16 + lr;
        const float bb = bias[gcol];
#pragma unroll
        for (int r = 0; r < 4; r++)
          out[(size_t)(grow0 + r) * E_ + gcol] = acc[i][j][r] + bb;
      }
    }
  } else if (w < 2) {
    // q/k: d-oct layout, coalesced ushort4 stores
    const int h = n0 / 192;
    const int bh = (m0 >> 11) * H_ + h;
    unsigned short* dst = (w == 0) ? qbf : kbf;
    const float sc = (w == 0) ? QSCALE : 1.0f;
#pragma unroll
    for (int i = 0; i < NI; i++) {
      const int s = (m0 & 2047) + wv * (BM / 4) + i * 16 + lr;
      const size_t rowb = (size_t)bh * 131072 + (size_t)(s >> 5) * 2048 + (s & 31) * 8
                        + (lg & 1) * 4;
#pragma unroll
      for (int j = 0; j < 4; j++) {
        float4 b4 = *(const float4*)&bias[n0 + j * 16 + lg * 4];
        ushort4 r;
        r.x = f2bf_fast((acc[i][j][0] + b4.x) * sc);
        r.y = f2bf_fast((acc[i][j][1] + b4.y) * sc);
        r.z = f2bf_fast((acc[i][j][2] + b4.z) * sc);
        r.w = f2bf_fast((acc[i][j][3] + b4.w) * sc);
        *(ushort4*)&dst[rowb + (size_t)(j * 2 + (lg >> 1)) * 256] = r;
      }
    }
  } else {
    // v: fp16 fragment layout (s-quads), half4 stores
    const int h = n0 / 192;
    const int bh = (m0 >> 11) * H_ + h;
#pragma unroll
    for (int i = 0; i < NI; i++) {
      const int s0 = (m0 & 2047) + wv * (BM / 4) + i * 16 + lg * 4;
      const int tb = s0 >> 6, kh = (s0 >> 5) & 1;
      const int kc2 = (s0 >> 4) & 1, l5v = (s0 >> 3) & 1, e0 = s0 & 7;
#pragma unroll
      for (int j = 0; j < 4; j++) {
        const int d = j * 16 + lr;
        const int db = d >> 5, l31v = d & 31;
        const float bb = bias[n0 + d];
        half2_t h01 = pkrtz(acc[i][j][0] + bb, acc[i][j][1] + bb);
        half2_t h23 = pkrtz(acc[i][j][2] + bb, acc[i][j][3] + bb);
        half4 hv = __builtin_shufflevector(h01, h23, 0, 1, 2, 3);
        const size_t idx =
            ((((((size_t)bh * 32 + tb) * 2 + kh) * 2 + db) * 2 + kc2) * 2 + l5v) * 256
            + (size_t)l31v * 8 + e0;
        *(half4*)&vth[idx] = hv;
      }
    }
  }
}

// ---------------------------------------------------------------------------
// Kernel 3: flash attention, software-pipelined. q/k in d-oct layout ->
// every fragment load is a single coalesced b128. exp = __builtin_amdgcn_exp2f.
// __launch_bounds__(256,6): VGPR 60 and LDS 25.5KB both allow 6 blocks/CU =
// grid/256 exactly -> full single-round residency, max latency overlap.
// ---------------------------------------------------------------------------
#define PROW 40   // P^T row stride in halves (80 B)

__global__ __launch_bounds__(256, 6) void attn_kernel(
    const unsigned short* __restrict__ qb, const unsigned short* __restrict__ kb,
    const _Float16* __restrict__ vth, unsigned short* __restrict__ ao) {
  // union: Ps (10 KB, K-loop) / C1+C2 combine buffers (25.5 KB, epilogue)
  __shared__ __align__(16) unsigned char smem[26112];
  _Float16* Ps = (_Float16*)smem;
  float* C1 = (float*)smem;        // [3][64][17] : oacc0 + l from waves 1,2,3
  float* C2 = C1 + 3 * 64 * 17;    // [3][64][17] : oacc1 + l from waves 0,2,3

  const int t = threadIdx.x;
  const int lane = t & 63, wv = t >> 6;
  const int l31 = lane & 31, l5 = lane >> 5;

  // XCD swizzle: id%8 = XCD -> 3 heads per XCD stay L2-resident
  const int id = blockIdx.x;
  const int bh = (id & 7) * 3 + ((id >> 3) >> 6);
  const int qt = (id >> 3) & 63;
  const int b = bh / H_, h = bh % H_;
  const int q0 = qt * 32;

  // Q fragments (B-operand, 32 q-rows): single b128 each (d-oct layout)
  short8 qf[4];
  {
    const unsigned short* qp = qb + (size_t)bh * 131072 + (size_t)qt * 2048 + l31 * 8;
#pragma unroll
    for (int kc = 0; kc < 4; kc++)
      qf[kc] = *(const short8*)(qp + (kc * 2 + l5) * 256);
  }

  floatx16 oacc0 = (floatx16)0.0f;   // O^T d 0..31 (partial: this wave's keys)
  floatx16 oacc1 = (floatx16)0.0f;   // O^T d 32..63
  float lsum = 0.f;                  // partial denominator for q = l31

  // this wave's key slice (32-key tiles): kt32 = 2*(wv>>1) + (wv&1)
  const unsigned short* kpb =
      kb + (size_t)bh * 131072 + (size_t)(2 * (wv >> 1) + (wv & 1)) * 2048 + l31 * 8;
  const _Float16* vpb =
      vth + (size_t)(bh * 32 + (wv >> 1)) * 4096 + (size_t)(wv & 1) * 2048 + (size_t)lane * 8;
  _Float16* PsW = Ps + wv * 32 * PROW;

#define LDK(kfv, tb2)                                                          \
  {                                                                            \
    const unsigned short* _p = kpb + (size_t)(tb2) * 8192;                     \
    _Pragma("unroll")                                                          \
    for (int kc = 0; kc < 4; kc++)                                             \
      kfv[kc] = *(const short8*)(_p + (kc * 2 + l5) * 256);                    \
  }

  // ---- prologue: K(0) -> S(0); then K(1), V(0) in flight
  short8 kf[4];
  half8 vf[4];
  LDK(kf, 0);
  floatx16 sacc = (floatx16)0.0f;
#pragma unroll
  for (int kc = 0; kc < 4; kc++)
    sacc = __builtin_amdgcn_mfma_f32_32x32x16_bf16(kf[kc], qf[kc], sacc, 0, 0, 0);
  LDK(kf, 1);
#pragma unroll
  for (int j = 0; j < 4; j++) vf[j] = *(const half8*)(vpb + j * 512);

  for (int tb = 0; tb < 16; tb++) {
    // ---- exp(t) in place; l tree-sum (VALU; overlaps prior MFMA batch)
#pragma unroll
    for (int r = 0; r < 16; r++) sacc[r] = fexp2(sacc[r]);
    {
      float s01 = (sacc[0] + sacc[1]) + (sacc[2] + sacc[3]);
      float s23 = (sacc[4] + sacc[5]) + (sacc[6] + sacc[7]);
      float s45 = (sacc[8] + sacc[9]) + (sacc[10] + sacc[11]);
      float s67 = (sacc[12] + sacc[13]) + (sacc[14] + sacc[15]);
      lsum += (s01 + s23) + (s45 + s67);
    }
    // ---- pack to fp16, write P^T rows (wave-private LDS)
#pragma unroll
    for (int rq = 0; rq < 4; rq++) {
      half2_t a = pkrtz(sacc[rq * 4 + 0], sacc[rq * 4 + 1]);
      half2_t c = pkrtz(sacc[rq * 4 + 2], sacc[rq * 4 + 3]);
      half4 w = __builtin_shufflevector(a, c, 0, 1, 2, 3);
      *(half4*)&PsW[l31 * PROW + rq * 8 + l5 * 4] = w;   // keys 8rq+4l5..+3
    }
    // ---- read P^T as B-operand; same-wave DS ordering, no barrier
    const _Float16* prd = &PsW[l31 * PROW + l5 * 8];
    half8 pf0 = *(const half8*)(prd);        // keys  0..15
    half8 pf1 = *(const half8*)(prd + 16);   // keys 16..31

    // ---- PV(t)  (fp16 MFMA)
    oacc0 = __builtin_amdgcn_mfma_f32_32x32x16_f16(vf[0], pf0, oacc0, 0, 0, 0);
    oacc0 = __builtin_amdgcn_mfma_f32_32x32x16_f16(vf[1], pf1, oacc0, 0, 0, 0);
    oacc1 = __builtin_amdgcn_mfma_f32_32x32x16_f16(vf[2], pf0, oacc1, 0, 0, 0);
    oacc1 = __builtin_amdgcn_mfma_f32_32x32x16_f16(vf[3], pf1, oacc1, 0, 0, 0);

    if (tb != 15) {
      // ---- prefetch V(t+1) (distance 1: used by PV next iter)
      const _Float16* vt2 = vpb + (size_t)(tb + 1) * 8192;
#pragma unroll
      for (int j = 0; j < 4; j++) vf[j] = *(const half8*)(vt2 + j * 512);
      // ---- QK(t+1) into sacc (kf = K(t+1), prefetched at distance 2)
      sacc = (floatx16)0.0f;
#pragma unroll
      for (int kc = 0; kc < 4; kc++)
        sacc = __builtin_amdgcn_mfma_f32_32x32x16_bf16(kf[kc], qf[kc], sacc, 0, 0, 0);
      // ---- prefetch K(t+2)
      LDK(kf, (tb + 2) & 15);
    }
  }

  // ---- combine the two key-halves within this wave's l (l5 pair)
  const float l2 = lsum + __shfl_xor(lsum, 32);

  // ---- 4-way key combine across waves (linear), normalize, store
  __syncthreads();  // all P reads done before overwriting Ps with C1/C2
  if (wv > 0) {
    float* c = &C1[(size_t)((wv - 1) * 64 + lane) * 17];
#pragma unroll
    for (int j = 0; j < 16; j++) c[j] = oacc0[j];
    c[16] = l2;
  }
  if (wv != 1) {
    const int slot = (wv == 0) ? 0 : wv - 1;
    float* c = &C2[(size_t)(slot * 64 + lane) * 17];
#pragma unroll
    for (int j = 0; j < 16; j++) c[j] = oacc1[j];
    c[16] = l2;
  }
  __syncthreads();
  if (wv < 2) {
    float o[16];
    float L;
    if (wv == 0) {
      L = l2;
#pragma unroll
      for (int j = 0; j < 16; j++) o[j] = oacc0[j];
#pragma unroll
      for (int i = 0; i < 3; i++) {
        const float* c = &C1[(size_t)(i * 64 + lane) * 17];
#pragma unroll
        for (int j = 0; j < 16; j++) o[j] += c[j];
        L += c[16];
      }
    } else {
      L = l2;
#pragma unroll
      for (int j = 0; j < 16; j++) o[j] = oacc1[j];
#pragma unroll
      for (int i = 0; i < 3; i++) {
        const float* c = &C2[(size_t)(i * 64 + lane) * 17];
#pragma unroll
        for (int j = 0; j < 16; j++) o[j] += c[j];
        L += c[16];
      }
    }
    const float inv = 1.0f / L;
    const int row = q0 + l31;
    const int dbase = wv * 32;  // wave 0 -> d 0..31, wave 1 -> d 32..63
    unsigned short* arow = &ao[((size_t)(b * S_ + row)) * E_ + h * HD_ + dbase];
#pragma unroll
    for (int a = 0; a < 4; a++) {
      ushort4 s;
      s.x = f2bf(o[a * 4 + 0] * inv);
      s.y = f2bf(o[a * 4 + 1] * inv);
      s.z = f2bf(o[a * 4 + 2] * inv);
      s.w = f2bf(o[a * 4 + 3] * inv);
      // d = 8a + 4*l5 + 0..3
      *(ushort4*)&arow[8 * a + 4 * l5] = s;
    }
  }
}

// ---------------------------------------------------------------------------
extern "C" void kernel_launch(void* const* d_in, const int* in_sizes, int n_in,
                              void* d_out, int out_size, void* d_ws, size_t ws_size,
                              hipStream_t stream) {
  const float* x     = (const float*)d_in[0];
  const float* gamma = (const float*)d_in[1];
  const float* beta  = (const float*)d_in[2];
  const float* Wqkv  = (const float*)d_in[3];
  const float* bqkv  = (const float*)d_in[4];
  const float* Wo    = (const float*)d_in[5];
  const float* bo    = (const float*)d_in[6];
  float* out = (float*)d_out;

  const size_t SZ = (size_t)M_ * E_;
  unsigned short* xnb = (unsigned short*)d_ws;
  unsigned short* qbf = xnb + SZ;
  unsigned short* kbf = qbf + SZ;
  _Float16*       vth = (_Float16*)(kbf + SZ);
  unsigned short* aob = (unsigned short*)(vth + SZ);
  unsigned short* wqf = aob + SZ;
  unsigned short* wof = wqf + (size_t)N3E * E_;

  // fused LN (1024 blocks) + fragment-order weight converts (1152 blocks)
  const int cvblocks = (NPQ + NPO) / 256;  // 1152
  aux_kernel<<<M_ / 4 + cvblocks, 256, 0, stream>>>(
      x, gamma, beta, xnb, Wqkv, Wo, wqf, wof);

  dim3 g_qkv(M_ / 128, N3E / 64);   // (32, 36) = 1152 blocks
  bgemm_kernel<2><<<g_qkv, 256, 0, stream>>>(xnb, wqf, bqkv, 0, qbf, kbf, vth, nullptr);

  attn_kernel<<<1536, 256, 0, stream>>>(qbf, kbf, vth, aob);

  dim3 g_out(M_ / 64, E_ / 64);     // (64, 12) = 768 blocks
  bgemm_kernel<1><<<g_out, 256, 0, stream>>>(aob, wof, bo, 1, nullptr, nullptr, nullptr, out);
}

// Round 15
// 168.929 us; speedup vs baseline: 1.6092x; 1.6092x over previous
//
#include <hip/hip_runtime.h>
#include <math.h>

// Problem constants
#define B_  2
#define S_  2048
#define E_  768
#define H_  12
#define HD_ 64
#define M_  (B_ * S_)     // 4096 rows
#define N3E (3 * E_)      // 2304

typedef __attribute__((ext_vector_type(8)))  short short8;      // 8 bf16
typedef __attribute__((ext_vector_type(8)))  _Float16 half8;    // 8 fp16
typedef __attribute__((ext_vector_type(4)))  _Float16 half4;
typedef __attribute__((ext_vector_type(2)))  _Float16 half2_t;
typedef __attribute__((ext_vector_type(4)))  float floatx4;     // 16x16 MFMA C/D
typedef __attribute__((ext_vector_type(16))) float floatx16;    // 32x32 MFMA C/D

// fold 1/sqrt(64) * log2(e) into q so softmax is a bare v_exp_f32 (exp2)
#define QSCALE 0.18033688011112042f

// packs per 64-row n-tile of fragment-ordered weights: 12 kb * 2 kk * 4 j * 64
#define WTILE 6144
#define NPQ   (36 * WTILE)   // Wqkv packs = 221184
#define NPO   (12 * WTILE)   // Wo packs   = 73728

// round-to-nearest-even fp32 -> bf16
__device__ inline unsigned short f2bf(float f) {
  union { float f; unsigned u; } a; a.f = f;
  unsigned r = a.u + 0x7fff + ((a.u >> 16) & 1);
  return (unsigned short)(r >> 16);
}
// round-half-up (2 VALU ops; still <= 0.5 ulp)
__device__ inline unsigned short f2bf_fast(float f) {
  union { float f; unsigned u; } a; a.f = f;
  return (unsigned short)((a.u + 0x8000u) >> 16);
}
// packed fp32x2 -> fp16x2 (single v_cvt_pkrtz_f16_f32)
__device__ inline half2_t pkrtz(float a, float b) {
  return __builtin_bit_cast(half2_t, __builtin_amdgcn_cvt_pkrtz(a, b));
}
// raw v_exp_f32 via the intrinsic (compiler-managed hazards; R12's inline-asm
// version corrupted results — hazard recognizer can't see through asm)
__device__ inline float fexp2(float x) { return __builtin_amdgcn_exp2f(x); }

// ---------------------------------------------------------------------------
// Kernel 1: fused aux pass.
//  blocks [0,1024):    LayerNorm -> bf16 xn (one wave per row)
//  blocks [1024,2176): convert Wqkv/Wo fp32 -> bf16 in MFMA-FRAGMENT order
// ---------------------------------------------------------------------------
__global__ __launch_bounds__(256) void aux_kernel(
    const float* __restrict__ x, const float* __restrict__ gamma,
    const float* __restrict__ beta, unsigned short* __restrict__ xnb,
    const float* __restrict__ Wqkv, const float* __restrict__ Wo,
    unsigned short* __restrict__ wqf, unsigned short* __restrict__ wof) {
  const int bid = blockIdx.x;
  if (bid < M_ / 4) {
    const int wv = threadIdx.x >> 6, lane = threadIdx.x & 63;
    const int row = bid * 4 + wv;
    const float* xr = x + (size_t)row * E_;

    float4 a = ((const float4*)xr)[lane];
    float4 b = ((const float4*)xr)[lane + 64];
    float4 c = ((const float4*)xr)[lane + 128];

    float s  = (a.x + a.y) + (a.z + a.w) + (b.x + b.y) + (b.z + b.w)
             + (c.x + c.y) + (c.z + c.w);
    float s2 = a.x*a.x + a.y*a.y + a.z*a.z + a.w*a.w
             + b.x*b.x + b.y*b.y + b.z*b.z + b.w*b.w
             + c.x*c.x + c.y*c.y + c.z*c.z + c.w*c.w;
#pragma unroll
    for (int o = 32; o > 0; o >>= 1) {
      s  += __shfl_xor(s, o);
      s2 += __shfl_xor(s2, o);
    }
    const float mu  = s * (1.0f / E_);
    const float var = s2 * (1.0f / E_) - mu * mu;
    const float rs  = rsqrtf(var + 1e-5f);

    const float4* gp = (const float4*)gamma;
    const float4* bp = (const float4*)beta;
    ushort4* xo = (ushort4*)(xnb + (size_t)row * E_);

    float4 vin[3] = {a, b, c};
#pragma unroll
    for (int j = 0; j < 3; j++) {
      float4 g = gp[lane + 64 * j];
      float4 be = bp[lane + 64 * j];
      float4 v = vin[j];
      ushort4 r;
      r.x = f2bf((v.x - mu) * rs * g.x + be.x);
      r.y = f2bf((v.y - mu) * rs * g.y + be.y);
      r.z = f2bf((v.z - mu) * rs * g.z + be.z);
      r.w = f2bf((v.w - mu) * rs * g.w + be.w);
      xo[lane + 64 * j] = r;
    }
  } else {
    int p = (bid - M_ / 4) * 256 + threadIdx.x;
    const float* src; unsigned short* dst;
    if (p < NPQ) { src = Wqkv; dst = wqf; }
    else         { src = Wo;   dst = wof; p -= NPQ; }
    const int nt = p / WTILE, r = p % WTILE;
    const int kb = r >> 9, r2 = r & 511;
    const int kk = r2 >> 8, r3 = r2 & 255;
    const int j = r3 >> 6, lane = r3 & 63;
    const int row = nt * 64 + j * 16 + (lane & 15);
    const int col = kb * 64 + kk * 32 + (lane >> 4) * 8;
    const float* sp = src + (size_t)row * 768 + col;
    float4 f0 = *(const float4*)(sp);
    float4 f1 = *(const float4*)(sp + 4);
    unsigned short* dp = dst + (size_t)p * 8;
    ushort4 r0, r1;
    r0.x = f2bf(f0.x); r0.y = f2bf(f0.y); r0.z = f2bf(f0.z); r0.w = f2bf(f0.w);
    r1.x = f2bf(f1.x); r1.y = f2bf(f1.y); r1.z = f2bf(f1.z); r1.w = f2bf(f1.w);
    *(ushort4*)(dp)     = r0;
    *(ushort4*)(dp + 4) = r1;
  }
}

// ---------------------------------------------------------------------------
// Kernel 2/4: bf16 MFMA GEMM with DIRECT global B-fragment loads.
// NI=2: 128-row tiles (QKV); NI=1: 64-row tiles (proj).
// mode 0 epilogues: q/k via swapped mfma -> d-OCT layout
//   [bh][s>>5][d>>3][s&31][8]; v -> fp16 frag layout.
// mode 1: fp32 out[M][768] = C + bias.
// ---------------------------------------------------------------------------
template <int NI>
__global__ __launch_bounds__(256) void bgemm_kernel(
    const unsigned short* __restrict__ A, const unsigned short* __restrict__ Wf,
    const float* __restrict__ bias, int mode,
    unsigned short* __restrict__ qbf, unsigned short* __restrict__ kbf,
    _Float16* __restrict__ vth, float* __restrict__ out) {
  constexpr int BM = 64 * NI;
  __shared__ __align__(16) unsigned short As[BM * 64];

  const int t  = threadIdx.x;
  const int ln = t & 63, wv = t >> 6;
  const int lr = ln & 15, lg = ln >> 4;
  const int m0 = blockIdx.x * BM, n0 = blockIdx.y * 64;
  const int w  = (mode == 1) ? 3 : (blockIdx.y % 3);

  const int srow = ln >> 3;          // 0..7
  const int scol = (ln & 7) * 8;     // k-offset

  const unsigned short* Ag = A + (size_t)(m0 + wv * (BM / 4) + srow) * 768 + scol;
  const unsigned short* Wt = Wf + (size_t)blockIdx.y * (WTILE * 8);

  floatx4 acc[NI][4];
#pragma unroll
  for (int i = 0; i < NI; i++)
#pragma unroll
    for (int j = 0; j < 4; j++) acc[i][j] = (floatx4){0.f, 0.f, 0.f, 0.f};

  for (int kb = 0; kb < 12; kb++) {
    __syncthreads();
#pragma unroll
    for (int j = 0; j < BM / 32; j++)
      __builtin_amdgcn_global_load_lds(
          (const __attribute__((address_space(1))) void*)(Ag + kb * 64 + j * 8 * 768),
          (__attribute__((address_space(3))) void*)(&As[(wv * (BM / 4) + j * 8) * 64]),
          16, 0, 0);
    // B fragments straight from global; drained by the barrier's vmcnt(0).
    short8 bfr[8];
#pragma unroll
    for (int u = 0; u < 8; u++)
      bfr[u] = *(const short8*)&Wt[(size_t)kb * 4096 + u * 512 + ln * 8];
    __syncthreads();

#pragma unroll
    for (int kk = 0; kk < 2; kk++) {
      short8 af[NI];
#pragma unroll
      for (int i = 0; i < NI; i++)
        af[i] = *(const short8*)&As[(wv * (BM / 4) + i * 16 + lr) * 64 + kk * 32 + lg * 8];
      if (w < 2) {  // swapped: C/D rows = n(d), cols = m(s)
#pragma unroll
        for (int i = 0; i < NI; i++)
#pragma unroll
          for (int j = 0; j < 4; j++)
            acc[i][j] = __builtin_amdgcn_mfma_f32_16x16x32_bf16(bfr[kk * 4 + j], af[i], acc[i][j], 0, 0, 0);
      } else {      // normal: C/D rows = m(s), cols = n(d)
#pragma unroll
        for (int i = 0; i < NI; i++)
#pragma unroll
          for (int j = 0; j < 4; j++)
            acc[i][j] = __builtin_amdgcn_mfma_f32_16x16x32_bf16(af[i], bfr[kk * 4 + j], acc[i][j], 0, 0, 0);
      }
    }
  }

  if (mode == 1) {
#pragma unroll
    for (int i = 0; i < NI; i++) {
      const int grow0 = m0 + wv * (BM / 4) + i * 16 + lg * 4;
#pragma unroll
      for (int j = 0; j < 4; j++) {
        const int gcol = n0 + j * 16 + lr;
        const float bb = bias[gcol];
#pragma unroll
        for (int r = 0; r < 4; r++)
          out[(size_t)(grow0 + r) * E_ + gcol] = acc[i][j][r] + bb;
      }
    }
  } else if (w < 2) {
    // q/k: d-oct layout, coalesced ushort4 stores
    const int h = n0 / 192;
    const int bh = (m0 >> 11) * H_ + h;
    unsigned short* dst = (w == 0) ? qbf : kbf;
    const float sc = (w == 0) ? QSCALE : 1.0f;
#pragma unroll
    for (int i = 0; i < NI; i++) {
      const int s = (m0 & 2047) + wv * (BM / 4) + i * 16 + lr;
      const size_t rowb = (size_t)bh * 131072 + (size_t)(s >> 5) * 2048 + (s & 31) * 8
                        + (lg & 1) * 4;
#pragma unroll
      for (int j = 0; j < 4; j++) {
        float4 b4 = *(const float4*)&bias[n0 + j * 16 + lg * 4];
        ushort4 r;
        r.x = f2bf_fast((acc[i][j][0] + b4.x) * sc);
        r.y = f2bf_fast((acc[i][j][1] + b4.y) * sc);
        r.z = f2bf_fast((acc[i][j][2] + b4.z) * sc);
        r.w = f2bf_fast((acc[i][j][3] + b4.w) * sc);
        *(ushort4*)&dst[rowb + (size_t)(j * 2 + (lg >> 1)) * 256] = r;
      }
    }
  } else {
    // v: fp16 fragment layout (s-quads), half4 stores
    const int h = n0 / 192;
    const int bh = (m0 >> 11) * H_ + h;
#pragma unroll
    for (int i = 0; i < NI; i++) {
      const int s0 = (m0 & 2047) + wv * (BM / 4) + i * 16 + lg * 4;
      const int tb = s0 >> 6, kh = (s0 >> 5) & 1;
      const int kc2 = (s0 >> 4) & 1, l5v = (s0 >> 3) & 1, e0 = s0 & 7;
#pragma unroll
      for (int j = 0; j < 4; j++) {
        const int d = j * 16 + lr;
        const int db = d >> 5, l31v = d & 31;
        const float bb = bias[n0 + d];
        half2_t h01 = pkrtz(acc[i][j][0] + bb, acc[i][j][1] + bb);
        half2_t h23 = pkrtz(acc[i][j][2] + bb, acc[i][j][3] + bb);
        half4 hv = __builtin_shufflevector(h01, h23, 0, 1, 2, 3);
        const size_t idx =
            ((((((size_t)bh * 32 + tb) * 2 + kh) * 2 + db) * 2 + kc2) * 2 + l5v) * 256
            + (size_t)l31v * 8 + e0;
        *(half4*)&vth[idx] = hv;
      }
    }
  }
}

// ---------------------------------------------------------------------------
// Kernel 3: flash attention, software-pipelined. q/k in d-oct layout ->
// every fragment load is a single coalesced b128. exp = __builtin_amdgcn_exp2f.
// __launch_bounds__(256,4): R14 showed (256,6) caps VGPR at 40 -> accumulator
// spills (210 MB scratch traffic). LDS halved to 13 KB via two-phase combine
// so LDS never caps co-residency below what VGPR=60 allows.
// ---------------------------------------------------------------------------
#define PROW 40   // P^T row stride in halves (80 B)

__global__ __launch_bounds__(256, 4) void attn_kernel(
    const unsigned short* __restrict__ qb, const unsigned short* __restrict__ kb,
    const _Float16* __restrict__ vth, unsigned short* __restrict__ ao) {
  // union: Ps (10240 B, K-loop) / C combine buffer (13056 B, epilogue 2-phase)
  __shared__ __align__(16) unsigned char smem[13056];
  _Float16* Ps = (_Float16*)smem;
  float* C = (float*)smem;         // [3][64][17] : per-phase partials + l

  const int t = threadIdx.x;
  const int lane = t & 63, wv = t >> 6;
  const int l31 = lane & 31, l5 = lane >> 5;

  // XCD swizzle: id%8 = XCD -> 3 heads per XCD stay L2-resident
  const int id = blockIdx.x;
  const int bh = (id & 7) * 3 + ((id >> 3) >> 6);
  const int qt = (id >> 3) & 63;
  const int b = bh / H_, h = bh % H_;
  const int q0 = qt * 32;

  // Q fragments (B-operand, 32 q-rows): single b128 each (d-oct layout)
  short8 qf[4];
  {
    const unsigned short* qp = qb + (size_t)bh * 131072 + (size_t)qt * 2048 + l31 * 8;
#pragma unroll
    for (int kc = 0; kc < 4; kc++)
      qf[kc] = *(const short8*)(qp + (kc * 2 + l5) * 256);
  }

  floatx16 oacc0 = (floatx16)0.0f;   // O^T d 0..31 (partial: this wave's keys)
  floatx16 oacc1 = (floatx16)0.0f;   // O^T d 32..63
  float lsum = 0.f;                  // partial denominator for q = l31

  // this wave's key slice (32-key tiles): kt32 = 2*(wv>>1) + (wv&1)
  const unsigned short* kpb =
      kb + (size_t)bh * 131072 + (size_t)(2 * (wv >> 1) + (wv & 1)) * 2048 + l31 * 8;
  const _Float16* vpb =
      vth + (size_t)(bh * 32 + (wv >> 1)) * 4096 + (size_t)(wv & 1) * 2048 + (size_t)lane * 8;
  _Float16* PsW = Ps + wv * 32 * PROW;

#define LDK(kfv, tb2)                                                          \
  {                                                                            \
    const unsigned short* _p = kpb + (size_t)(tb2) * 8192;                     \
    _Pragma("unroll")                                                          \
    for (int kc = 0; kc < 4; kc++)                                             \
      kfv[kc] = *(const short8*)(_p + (kc * 2 + l5) * 256);                    \
  }

  // ---- prologue: K(0) -> S(0); then K(1), V(0) in flight
  short8 kf[4];
  half8 vf[4];
  LDK(kf, 0);
  floatx16 sacc = (floatx16)0.0f;
#pragma unroll
  for (int kc = 0; kc < 4; kc++)
    sacc = __builtin_amdgcn_mfma_f32_32x32x16_bf16(kf[kc], qf[kc], sacc, 0, 0, 0);
  LDK(kf, 1);
#pragma unroll
  for (int j = 0; j < 4; j++) vf[j] = *(const half8*)(vpb + j * 512);

  for (int tb = 0; tb < 16; tb++) {
    // ---- exp(t) in place; l tree-sum (VALU; overlaps prior MFMA batch)
#pragma unroll
    for (int r = 0; r < 16; r++) sacc[r] = fexp2(sacc[r]);
    {
      float s01 = (sacc[0] + sacc[1]) + (sacc[2] + sacc[3]);
      float s23 = (sacc[4] + sacc[5]) + (sacc[6] + sacc[7]);
      float s45 = (sacc[8] + sacc[9]) + (sacc[10] + sacc[11]);
      float s67 = (sacc[12] + sacc[13]) + (sacc[14] + sacc[15]);
      lsum += (s01 + s23) + (s45 + s67);
    }
    // ---- pack to fp16, write P^T rows (wave-private LDS)
#pragma unroll
    for (int rq = 0; rq < 4; rq++) {
      half2_t a = pkrtz(sacc[rq * 4 + 0], sacc[rq * 4 + 1]);
      half2_t c = pkrtz(sacc[rq * 4 + 2], sacc[rq * 4 + 3]);
      half4 w = __builtin_shufflevector(a, c, 0, 1, 2, 3);
      *(half4*)&PsW[l31 * PROW + rq * 8 + l5 * 4] = w;   // keys 8rq+4l5..+3
    }
    // ---- read P^T as B-operand; same-wave DS ordering, no barrier
    const _Float16* prd = &PsW[l31 * PROW + l5 * 8];
    half8 pf0 = *(const half8*)(prd);        // keys  0..15
    half8 pf1 = *(const half8*)(prd + 16);   // keys 16..31

    // ---- PV(t)  (fp16 MFMA)
    oacc0 = __builtin_amdgcn_mfma_f32_32x32x16_f16(vf[0], pf0, oacc0, 0, 0, 0);
    oacc0 = __builtin_amdgcn_mfma_f32_32x32x16_f16(vf[1], pf1, oacc0, 0, 0, 0);
    oacc1 = __builtin_amdgcn_mfma_f32_32x32x16_f16(vf[2], pf0, oacc1, 0, 0, 0);
    oacc1 = __builtin_amdgcn_mfma_f32_32x32x16_f16(vf[3], pf1, oacc1, 0, 0, 0);

    if (tb != 15) {
      // ---- prefetch V(t+1) (distance 1: used by PV next iter)
      const _Float16* vt2 = vpb + (size_t)(tb + 1) * 8192;
#pragma unroll
      for (int j = 0; j < 4; j++) vf[j] = *(const half8*)(vt2 + j * 512);
      // ---- QK(t+1) into sacc (kf = K(t+1), prefetched at distance 2)
      sacc = (floatx16)0.0f;
#pragma unroll
      for (int kc = 0; kc < 4; kc++)
        sacc = __builtin_amdgcn_mfma_f32_32x32x16_bf16(kf[kc], qf[kc], sacc, 0, 0, 0);
      // ---- prefetch K(t+2)
      LDK(kf, (tb + 2) & 15);
    }
  }

  // ---- combine the two key-halves within this wave's l (l5 pair)
  const float l2 = lsum + __shfl_xor(lsum, 32);

  // ---- 4-way key combine, TWO PHASES through one 13 KB buffer
  // phase 1: waves 1,2,3 post oacc0 + l; wave 0 reduces, stores d 0..31
  __syncthreads();  // all P reads done before overwriting Ps with C
  if (wv > 0) {
    float* c = &C[(size_t)((wv - 1) * 64 + lane) * 17];
#pragma unroll
    for (int j = 0; j < 16; j++) c[j] = oacc0[j];
    c[16] = l2;
  }
  __syncthreads();
  if (wv == 0) {
    float o[16];
    float L = l2;
#pragma unroll
    for (int j = 0; j < 16; j++) o[j] = oacc0[j];
#pragma unroll
    for (int i = 0; i < 3; i++) {
      const float* c = &C[(size_t)(i * 64 + lane) * 17];
#pragma unroll
      for (int j = 0; j < 16; j++) o[j] += c[j];
      L += c[16];
    }
    const float inv = 1.0f / L;
    const int row = q0 + l31;
    unsigned short* arow = &ao[((size_t)(b * S_ + row)) * E_ + h * HD_];
#pragma unroll
    for (int a = 0; a < 4; a++) {
      ushort4 s;
      s.x = f2bf(o[a * 4 + 0] * inv);
      s.y = f2bf(o[a * 4 + 1] * inv);
      s.z = f2bf(o[a * 4 + 2] * inv);
      s.w = f2bf(o[a * 4 + 3] * inv);
      *(ushort4*)&arow[8 * a + 4 * l5] = s;   // d = 8a + 4*l5 + 0..3
    }
  }
  // phase 2: waves 0,2,3 post oacc1 + l; wave 1 reduces, stores d 32..63
  __syncthreads();  // wave 0 finished reading C
  if (wv != 1) {
    const int slot = (wv == 0) ? 0 : wv - 1;
    float* c = &C[(size_t)(slot * 64 + lane) * 17];
#pragma unroll
    for (int j = 0; j < 16; j++) c[j] = oacc1[j];
    c[16] = l2;
  }
  __syncthreads();
  if (wv == 1) {
    float o[16];
    float L = l2;
#pragma unroll
    for (int j = 0; j < 16; j++) o[j] = oacc1[j];
#pragma unroll
    for (int i = 0; i < 3; i++) {
      const float* c = &C[(size_t)(i * 64 + lane) * 17];
#pragma unroll
      for (int j = 0; j < 16; j++) o[j] += c[j];
      L += c[16];
    }
    const float inv = 1.0f / L;
    const int row = q0 + l31;
    unsigned short* arow = &ao[((size_t)(b * S_ + row)) * E_ + h * HD_ + 32];
#pragma unroll
    for (int a = 0; a < 4; a++) {
      ushort4 s;
      s.x = f2bf(o[a * 4 + 0] * inv);
      s.y = f2bf(o[a * 4 + 1] * inv);
      s.z = f2bf(o[a * 4 + 2] * inv);
      s.w = f2bf(o[a * 4 + 3] * inv);
      *(ushort4*)&arow[8 * a + 4 * l5] = s;   // d = 32 + 8a + 4*l5 + 0..3
    }
  }
}

// ---------------------------------------------------------------------------
extern "C" void kernel_launch(void* const* d_in, const int* in_sizes, int n_in,
                              void* d_out, int out_size, void* d_ws, size_t ws_size,
                              hipStream_t stream) {
  const float* x     = (const float*)d_in[0];
  const float* gamma = (const float*)d_in[1];
  const float* beta  = (const float*)d_in[2];
  const float* Wqkv  = (const float*)d_in[3];
  const float* bqkv  = (const float*)d_in[4];
  const float* Wo    = (const float*)d_in[5];
  const float* bo    = (const float*)d_in[6];
  float* out = (float*)d_out;

  const size_t SZ = (size_t)M_ * E_;
  unsigned short* xnb = (unsigned short*)d_ws;
  unsigned short* qbf = xnb + SZ;
  unsigned short* kbf = qbf + SZ;
  _Float16*       vth = (_Float16*)(kbf + SZ);
  unsigned short* aob = (unsigned short*)(vth + SZ);
  unsigned short* wqf = aob + SZ;
  unsigned short* wof = wqf + (size_t)N3E * E_;

  // fused LN (1024 blocks) + fragment-order weight converts (1152 blocks)
  const int cvblocks = (NPQ + NPO) / 256;  // 1152
  aux_kernel<<<M_ / 4 + cvblocks, 256, 0, stream>>>(
      x, gamma, beta, xnb, Wqkv, Wo, wqf, wof);

  dim3 g_qkv(M_ / 128, N3E / 64);   // (32, 36) = 1152 blocks
  bgemm_kernel<2><<<g_qkv, 256, 0, stream>>>(xnb, wqf, bqkv, 0, qbf, kbf, vth, nullptr);

  attn_kernel<<<1536, 256, 0, stream>>>(qbf, kbf, vth, aob);

  dim3 g_out(M_ / 64, E_ / 64);     // (64, 12) = 768 blocks
  bgemm_kernel<1><<<g_out, 256, 0, stream>>>(aob, wof, bo, 1, nullptr, nullptr, nullptr, out);
}